// Round 3
// baseline (691.465 us; speedup 1.0000x reference)
//
#include <hip/hip_runtime.h>

#define N_NODES  100000
#define N_EDGES  1600000
#define N_GRAPHS 128
#define NB1      391        // ceil(100000/256)

// ---------------- histogram kernels ----------------
__global__ __launch_bounds__(256) void k_deg(const int* __restrict__ dst, int* __restrict__ deg) {
    int e = blockIdx.x * 256 + threadIdx.x;
    if (e < N_EDGES) atomicAdd(&deg[dst[e]], 1);
}

__global__ __launch_bounds__(256) void k_cnt(const int* __restrict__ batch, int* __restrict__ bhist) {
    int n = blockIdx.x * 256 + threadIdx.x;
    if (n < N_NODES) atomicAdd(&bhist[batch[n]], 1);
}

__global__ __launch_bounds__(256) void k_dinv(const int* __restrict__ deg, float* __restrict__ dinv) {
    int n = blockIdx.x * 256 + threadIdx.x;
    if (n < N_NODES) dinv[n] = rsqrtf((float)(deg[n] + 1));
}

// ---------------- scan (3-stage) ----------------
__global__ __launch_bounds__(256) void k_scan1(const int* __restrict__ deg, int* __restrict__ bsum) {
    __shared__ int sh[256];
    int t = threadIdx.x, n = blockIdx.x * 256 + t;
    sh[t] = (n < N_NODES) ? deg[n] : 0;
    __syncthreads();
    for (int off = 128; off > 0; off >>= 1) {
        if (t < off) sh[t] += sh[t + off];
        __syncthreads();
    }
    if (t == 0) bsum[blockIdx.x] = sh[0];
}

// one block, 512 threads: scan bsum[391] -> bsumOff (exclusive) + row[N]=total;
// scan bhist[128] -> boff/bcur
__global__ __launch_bounds__(512) void k_scan2(const int* __restrict__ bsum, int* __restrict__ bsumOff,
                                               int* __restrict__ row, const int* __restrict__ bhist,
                                               int* __restrict__ boff, int* __restrict__ bcur) {
    __shared__ int s1[512], s2[512];
    int t = threadIdx.x;
    int v = (t < NB1) ? bsum[t] : 0;
    s1[t] = v; __syncthreads();
    int* pa = s1; int* pb = s2;
    for (int off = 1; off < 512; off <<= 1) {
        int x = pa[t];
        if (t >= off) x += pa[t - off];
        pb[t] = x; __syncthreads();
        int* tmp = pa; pa = pb; pb = tmp;
    }
    if (t < NB1) bsumOff[t] = pa[t] - v;
    if (t == 0) row[N_NODES] = pa[511];
    __syncthreads();
    int hv = (t < N_GRAPHS) ? bhist[t] : 0;
    pa[t] = hv; __syncthreads();   // pa/pb reuse, fresh scan
    int* qa = pa; int* qb = pb;
    for (int off = 1; off < 512; off <<= 1) {
        int x = qa[t];
        if (t >= off) x += qa[t - off];
        qb[t] = x; __syncthreads();
        int* tmp = qa; qa = qb; qb = tmp;
    }
    if (t < N_GRAPHS) { int e = qa[t] - hv; boff[t] = e; bcur[t] = e; }
    if (t == 0) boff[N_GRAPHS] = N_NODES;
}

// per-block exclusive scan + global offset; writes row[] and cur[] (cur aliases deg: read-own-then-write)
__global__ __launch_bounds__(256) void k_scan3(const int* __restrict__ deg, const int* __restrict__ bsumOff,
                                               int* __restrict__ row, int* __restrict__ cur) {
    __shared__ int a1[256], a2[256];
    int t = threadIdx.x, n = blockIdx.x * 256 + t;
    int v = (n < N_NODES) ? deg[n] : 0;
    a1[t] = v; __syncthreads();
    int* pa = a1; int* pb = a2;
    for (int off = 1; off < 256; off <<= 1) {
        int x = pa[t];
        if (t >= off) x += pa[t - off];
        pb[t] = x; __syncthreads();
        int* tmp = pa; pa = pb; pb = tmp;
    }
    int excl = pa[t] - v + bsumOff[blockIdx.x];
    if (n < N_NODES) { row[n] = excl; cur[n] = excl; }
}

// ---------------- CSR scatter ----------------
__global__ __launch_bounds__(256) void k_escatter(const int* __restrict__ src, const int* __restrict__ dst,
                                                  int* __restrict__ cur, int* __restrict__ srcS) {
    int e = blockIdx.x * 256 + threadIdx.x;
    if (e < N_EDGES) {
        int pos = atomicAdd(&cur[dst[e]], 1);
        srcS[pos] = src[e];
    }
}

__global__ __launch_bounds__(256) void k_nscatter(const int* __restrict__ batch, int* __restrict__ bcur,
                                                  int* __restrict__ nodeSorted) {
    int n = blockIdx.x * 256 + threadIdx.x;
    if (n < N_NODES) {
        int pos = atomicAdd(&bcur[batch[n]], 1);
        nodeSorted[pos] = n;
    }
}

// ---------------- t1s = dinv * (x @ W1) ----------------
__global__ __launch_bounds__(256) void k_gemm1(const float* __restrict__ x, const float* __restrict__ W1,
                                               const float* __restrict__ dinv, float* __restrict__ t1s) {
    __shared__ float w[128 * 16];
    __shared__ float xs[16][132];
    int t = threadIdx.x;
    {
        const float4* wv = (const float4*)W1;
        ((float4*)w)[t * 2]     = wv[t * 2];
        ((float4*)w)[t * 2 + 1] = wv[t * 2 + 1];
    }
    int base = blockIdx.x * 16;
    {
        const float4* xv = (const float4*)(x + (size_t)base * 128);
        #pragma unroll
        for (int q = 0; q < 2; ++q) {
            int i4 = t * 2 + q;
            float4 v = xv[i4];
            int idx = i4 * 4;
            *((float4*)&xs[idx >> 7][idx & 127]) = v;
        }
    }
    __syncthreads();
    int nl = t >> 4, j = t & 15;
    int n = base + nl;
    const float4* xr = (const float4*)&xs[nl][0];
    float acc = 0.f;
    #pragma unroll
    for (int k4 = 0; k4 < 32; ++k4) {
        float4 v = xr[k4];
        acc += v.x * w[(k4 * 4 + 0) * 16 + j];
        acc += v.y * w[(k4 * 4 + 1) * 16 + j];
        acc += v.z * w[(k4 * 4 + 2) * 16 + j];
        acc += v.w * w[(k4 * 4 + 3) * 16 + j];
    }
    t1s[n * 16 + j] = dinv[n] * acc;
}

// ---------------- CSR gather: out = f(dinv[n]*(sum hs[src] + hs[n])) ----------------
// LAYER==1: out = dinv * relu(q + b1)   (produces h1s for layer 2)
// LAYER==2: out = q                      (q2 feeding W2)
template <int LAYER>
__global__ __launch_bounds__(256) void k_gather(const int* __restrict__ row, const int* __restrict__ srcS,
                                                const float* __restrict__ hs, const float* __restrict__ dinv,
                                                const float* __restrict__ b1, float* __restrict__ outp) {
    int t = threadIdx.x;
    int k = t & 15;
    int n = blockIdx.x * 16 + (t >> 4);
    int r0 = row[n], r1 = row[n + 1];
    float acc = hs[n * 16 + k];                 // self-loop term
    for (int base = r0; base < r1; base += 16) {
        int idx = base + k;
        int sv = (idx < r1) ? srcS[idx] : 0;    // coalesced 16-wide load of srcs
        int m = r1 - base; if (m > 16) m = 16;  // group-uniform
        for (int j = 0; j < m; ++j) {
            int s = __shfl(sv, j, 16);
            acc += hs[s * 16 + k];
        }
    }
    float dv = dinv[n];
    if (LAYER == 1) {
        float v = fmaxf(dv * acc + b1[k], 0.f);
        outp[n * 16 + k] = dv * v;
    } else {
        outp[n * 16 + k] = dv * acc;
    }
}

// ---------------- pooling: one block per graph, no atomics ----------------
__global__ __launch_bounds__(256) void k_pool(const float* __restrict__ q2, const float* __restrict__ W2,
                                              const float* __restrict__ b2, const int* __restrict__ boff,
                                              const int* __restrict__ nodeSorted, float* __restrict__ sums) {
    __shared__ float w[16 * 128];
    __shared__ float bsh[128];
    __shared__ float rows[8][16];
    __shared__ float red[256];
    int t = threadIdx.x, g = blockIdx.x;
    {
        const float4* wv = (const float4*)W2;
        ((float4*)w)[t * 2]     = wv[t * 2];
        ((float4*)w)[t * 2 + 1] = wv[t * 2 + 1];
    }
    if (t < 128) bsh[t] = b2[t];
    int s0 = boff[g], s1 = boff[g + 1];
    int half = t >> 7, j = t & 127;
    float acc = 0.f;
    for (int base = s0; base < s1; base += 8) {
        __syncthreads();
        if (t < 128) {
            int which = t >> 4, kk = t & 15;
            int idx = base + which;
            rows[which][kk] = (idx < s1) ? q2[nodeSorted[idx] * 16 + kk] : 0.f;
        }
        __syncthreads();
        #pragma unroll
        for (int q = 0; q < 4; ++q) {
            int which = half * 4 + q;
            if (base + which < s1) {
                float a = bsh[j];
                #pragma unroll
                for (int kk = 0; kk < 16; ++kk) a += rows[which][kk] * w[kk * 128 + j];
                acc += fmaxf(a, 0.f);
            }
        }
    }
    red[t] = acc; __syncthreads();
    if (t < 128) sums[g * 128 + t] = red[t] + red[t + 128];
}

// ---------------- fused MLP head + log_softmax: 128 blocks x 128 threads ----------------
__global__ __launch_bounds__(128) void k_head(const float* __restrict__ sums, const int* __restrict__ boff,
                                              const float* __restrict__ LW1, const float* __restrict__ Lb1,
                                              const float* __restrict__ LW2, const float* __restrict__ Lb2,
                                              float* __restrict__ out) {
    __shared__ float srow[128];
    __shared__ float z1s[128];
    __shared__ float zz[2];
    int g = blockIdx.x, t = threadIdx.x;
    int cnt = boff[g + 1] - boff[g];
    float rc = 1.0f / fmaxf((float)cnt, 1.0f);
    srow[t] = sums[g * 128 + t] * rc;
    __syncthreads();
    float a = Lb1[t];
    for (int k = 0; k < 128; ++k) a += srow[k] * LW1[k * 128 + t];
    z1s[t] = fmaxf(a, 0.f);
    __syncthreads();
    if (t < 2) {
        float z = Lb2[t];
        for (int jj = 0; jj < 128; ++jj) z += z1s[jj] * LW2[jj * 2 + t];
        zz[t] = z;
    }
    __syncthreads();
    if (t < 2) {
        float m = fmaxf(zz[0], zz[1]);
        float lse = m + logf(expf(zz[0] - m) + expf(zz[1] - m));
        out[g * 2 + t] = zz[t] - lse;
    }
}

extern "C" void kernel_launch(void* const* d_in, const int* in_sizes, int n_in,
                              void* d_out, int out_size, void* d_ws, size_t ws_size,
                              hipStream_t stream) {
    const float* x   = (const float*)d_in[0];
    const int* ei    = (const int*)d_in[1];
    const int* batch = (const int*)d_in[2];
    const float* W1  = (const float*)d_in[3];
    const float* b1  = (const float*)d_in[4];
    const float* W2  = (const float*)d_in[5];
    const float* b2  = (const float*)d_in[6];
    const float* LW1 = (const float*)d_in[7];
    const float* Lb1 = (const float*)d_in[8];
    const float* LW2 = (const float*)d_in[9];
    const float* Lb2 = (const float*)d_in[10];
    const int* src = ei;
    const int* dst = ei + N_EDGES;

    char* ws = (char*)d_ws;
    int*   deg     = (int*)(ws);                  // 400000 B  (later aliased as cur)
    int*   bhist   = (int*)(ws + 400000);         // 512 B
    int*   bsum    = (int*)(ws + 400512);         // 2048 B (pad 512)
    int*   bsumOff = (int*)(ws + 402560);         // 2048 B
    int*   boff    = (int*)(ws + 404608);         // 1024 B (129 ints)
    int*   bcur    = (int*)(ws + 405632);         // 512 B
    int*   row     = (int*)(ws + 406144);         // 400128 B (100001 ints)
    float* dinv    = (float*)(ws + 806272);       // 400000 B
    int*   nodeS   = (int*)(ws + 1206272);        // 400000 B
    int*   srcS    = (int*)(ws + 1606272);        // 6400000 B
    float* A       = (float*)(ws + 8006272);      // 6400000 B (t1s, then q2)
    float* B       = (float*)(ws + 14406272);     // 6400000 B (h1s)
    float* sums    = (float*)(ws + 20806272);     // 65536 B
    int*   cur     = deg;                         // alias: deg dead after scans
    float* out     = (float*)d_out;

    // zero atomic histogram targets (deg + bhist contiguous)
    hipMemsetAsync(ws, 0, 400512, stream);

    k_deg      <<<6250, 256, 0, stream>>>(dst, deg);
    k_cnt      <<<NB1,  256, 0, stream>>>(batch, bhist);
    k_dinv     <<<NB1,  256, 0, stream>>>(deg, dinv);
    k_scan1    <<<NB1,  256, 0, stream>>>(deg, bsum);
    k_scan2    <<<1,    512, 0, stream>>>(bsum, bsumOff, row, bhist, boff, bcur);
    k_scan3    <<<NB1,  256, 0, stream>>>(deg, bsumOff, row, cur);
    k_escatter <<<6250, 256, 0, stream>>>(src, dst, cur, srcS);
    k_nscatter <<<NB1,  256, 0, stream>>>(batch, bcur, nodeS);
    k_gemm1    <<<6250, 256, 0, stream>>>(x, W1, dinv, A);
    k_gather<1><<<6250, 256, 0, stream>>>(row, srcS, A, dinv, b1, B);
    k_gather<2><<<6250, 256, 0, stream>>>(row, srcS, B, dinv, b1, A);
    k_pool     <<<128,  256, 0, stream>>>(A, W2, b2, boff, nodeS, sums);
    k_head     <<<128,  128, 0, stream>>>(sums, boff, LW1, Lb1, LW2, Lb2, out);
}

// Round 4
// 540.359 us; speedup vs baseline: 1.2796x; 1.2796x over previous
//
#include <hip/hip_runtime.h>

#define N_NODES  100000
#define N_EDGES  1600000
#define N_GRAPHS 128
#define NB1      391        // ceil(100000/256)
#define NBE      6250       // 1600000/256

// ---- fused histograms: degree over dst + nodes-per-graph ----
__global__ __launch_bounds__(256) void k_hist(const int* __restrict__ dst, const int* __restrict__ batch,
                                              int* __restrict__ deg, int* __restrict__ bhist) {
    int b = blockIdx.x;
    if (b < NBE) {
        int e = b * 256 + threadIdx.x;          // exact
        atomicAdd(&deg[dst[e]], 1);
    } else {
        int n = (b - NBE) * 256 + threadIdx.x;
        if (n < N_NODES) atomicAdd(&bhist[batch[n]], 1);
    }
}

// ---- scan stage 1: per-block sums of deg ----
__global__ __launch_bounds__(256) void k_scan1(const int* __restrict__ deg, int* __restrict__ bsum) {
    __shared__ int sh[256];
    int t = threadIdx.x, n = blockIdx.x * 256 + t;
    sh[t] = (n < N_NODES) ? deg[n] : 0;
    __syncthreads();
    for (int off = 128; off > 0; off >>= 1) {
        if (t < off) sh[t] += sh[t + off];
        __syncthreads();
    }
    if (t == 0) bsum[blockIdx.x] = sh[0];
}

// ---- scan stage 2 (1 block, 512 thr): scan bsum[391]; scan bhist[128] -> boff/bcur ----
__global__ __launch_bounds__(512) void k_scan2(const int* __restrict__ bsum, int* __restrict__ bsumOff,
                                               int* __restrict__ row, const int* __restrict__ bhist,
                                               int* __restrict__ boff, int* __restrict__ bcur) {
    __shared__ int s1[512], s2[512];
    int t = threadIdx.x;
    int v = (t < NB1) ? bsum[t] : 0;
    s1[t] = v; __syncthreads();
    int* pa = s1; int* pb = s2;
    for (int off = 1; off < 512; off <<= 1) {
        int x = pa[t];
        if (t >= off) x += pa[t - off];
        pb[t] = x; __syncthreads();
        int* tmp = pa; pa = pb; pb = tmp;
    }
    if (t < NB1) bsumOff[t] = pa[t] - v;
    if (t == 0) row[N_NODES] = pa[511];
    __syncthreads();
    int hv = (t < N_GRAPHS) ? bhist[t] : 0;
    pa[t] = hv; __syncthreads();
    int* qa = pa; int* qb = pb;
    for (int off = 1; off < 512; off <<= 1) {
        int x = qa[t];
        if (t >= off) x += qa[t - off];
        qb[t] = x; __syncthreads();
        int* tmp = qa; qa = qb; qb = tmp;
    }
    if (t < N_GRAPHS) { int e = qa[t] - hv; boff[t] = e; bcur[t] = e; }
    if (t == 0) boff[N_GRAPHS] = N_NODES;
}

// ---- scan stage 3: row[] / cur[] + fused dinv ----
__global__ __launch_bounds__(256) void k_scan3(const int* __restrict__ deg, const int* __restrict__ bsumOff,
                                               int* __restrict__ row, int* __restrict__ cur,
                                               float* __restrict__ dinv) {
    __shared__ int a1[256], a2[256];
    int t = threadIdx.x, n = blockIdx.x * 256 + t;
    int v = (n < N_NODES) ? deg[n] : 0;
    a1[t] = v; __syncthreads();
    int* pa = a1; int* pb = a2;
    for (int off = 1; off < 256; off <<= 1) {
        int x = pa[t];
        if (t >= off) x += pa[t - off];
        pb[t] = x; __syncthreads();
        int* tmp = pa; pa = pb; pb = tmp;
    }
    int excl = pa[t] - v + bsumOff[blockIdx.x];
    if (n < N_NODES) {
        row[n] = excl; cur[n] = excl;
        dinv[n] = rsqrtf((float)(v + 1));
    }
}

// ---- fused CSR scatter (edges) + node sort-by-graph ----
__global__ __launch_bounds__(256) void k_scatter(const int* __restrict__ src, const int* __restrict__ dst,
                                                 int* __restrict__ cur, int* __restrict__ srcS,
                                                 const int* __restrict__ batch, int* __restrict__ bcur,
                                                 int* __restrict__ nodeS) {
    int b = blockIdx.x;
    if (b < NBE) {
        int e = b * 256 + threadIdx.x;
        int pos = atomicAdd(&cur[dst[e]], 1);
        srcS[pos] = src[e];
    } else {
        int n = (b - NBE) * 256 + threadIdx.x;
        if (n < N_NODES) {
            int pos = atomicAdd(&bcur[batch[n]], 1);
            nodeS[pos] = n;
        }
    }
}

// ---- t1s = dinv * (x @ W1) ----
__global__ __launch_bounds__(256) void k_gemm1(const float* __restrict__ x, const float* __restrict__ W1,
                                               const float* __restrict__ dinv, float* __restrict__ t1s) {
    __shared__ float w[128 * 16];
    __shared__ float xs[16][132];
    int t = threadIdx.x;
    {
        const float4* wv = (const float4*)W1;
        ((float4*)w)[t * 2]     = wv[t * 2];
        ((float4*)w)[t * 2 + 1] = wv[t * 2 + 1];
    }
    int base = blockIdx.x * 16;
    {
        const float4* xv = (const float4*)(x + (size_t)base * 128);
        #pragma unroll
        for (int q = 0; q < 2; ++q) {
            int i4 = t * 2 + q;
            float4 v = xv[i4];
            int idx = i4 * 4;
            *((float4*)&xs[idx >> 7][idx & 127]) = v;
        }
    }
    __syncthreads();
    int nl = t >> 4, j = t & 15;
    int n = base + nl;
    const float4* xr = (const float4*)&xs[nl][0];
    float acc = 0.f;
    #pragma unroll
    for (int k4 = 0; k4 < 32; ++k4) {
        float4 v = xr[k4];
        acc += v.x * w[(k4 * 4 + 0) * 16 + j];
        acc += v.y * w[(k4 * 4 + 1) * 16 + j];
        acc += v.z * w[(k4 * 4 + 2) * 16 + j];
        acc += v.w * w[(k4 * 4 + 3) * 16 + j];
    }
    t1s[n * 16 + j] = dinv[n] * acc;
}

// ---- CSR gather, 4 lanes/node, float4/lane, 4x unrolled independent gathers ----
// LAYER==1: out = dinv * relu(dinv*acc + b1)   LAYER==2: out = dinv*acc
template <int LAYER>
__global__ __launch_bounds__(256) void k_gather(const int* __restrict__ row, const int* __restrict__ srcS,
                                                const float4* __restrict__ hs4, const float* __restrict__ dinv,
                                                const float* __restrict__ b1, float4* __restrict__ out4) {
    int t = threadIdx.x;
    int q = t & 3;
    int n = blockIdx.x * 64 + (t >> 2);     // 1563 blocks
    if (n >= N_NODES) return;
    int r0 = row[n], r1 = row[n + 1];
    float4 a0 = hs4[(size_t)n * 4 + q];     // self-loop term
    float4 a1 = {0.f, 0.f, 0.f, 0.f};
    float4 a2 = {0.f, 0.f, 0.f, 0.f};
    float4 a3 = {0.f, 0.f, 0.f, 0.f};
    int i = r0;
    for (; i + 4 <= r1; i += 4) {
        int s0 = srcS[i], s1 = srcS[i + 1], s2 = srcS[i + 2], s3 = srcS[i + 3];
        float4 v0 = hs4[(size_t)s0 * 4 + q];
        float4 v1 = hs4[(size_t)s1 * 4 + q];
        float4 v2 = hs4[(size_t)s2 * 4 + q];
        float4 v3 = hs4[(size_t)s3 * 4 + q];
        a0.x += v0.x; a0.y += v0.y; a0.z += v0.z; a0.w += v0.w;
        a1.x += v1.x; a1.y += v1.y; a1.z += v1.z; a1.w += v1.w;
        a2.x += v2.x; a2.y += v2.y; a2.z += v2.z; a2.w += v2.w;
        a3.x += v3.x; a3.y += v3.y; a3.z += v3.z; a3.w += v3.w;
    }
    for (; i < r1; ++i) {
        int s = srcS[i];
        float4 v = hs4[(size_t)s * 4 + q];
        a0.x += v.x; a0.y += v.y; a0.z += v.z; a0.w += v.w;
    }
    float sx = (a0.x + a1.x) + (a2.x + a3.x);
    float sy = (a0.y + a1.y) + (a2.y + a3.y);
    float sz = (a0.z + a1.z) + (a2.z + a3.z);
    float sw = (a0.w + a1.w) + (a2.w + a3.w);
    float dv = dinv[n];
    float4 r;
    if (LAYER == 1) {
        const float4 bb = ((const float4*)b1)[q];
        r.x = dv * fmaxf(dv * sx + bb.x, 0.f);
        r.y = dv * fmaxf(dv * sy + bb.y, 0.f);
        r.z = dv * fmaxf(dv * sz + bb.z, 0.f);
        r.w = dv * fmaxf(dv * sw + bb.w, 0.f);
    } else {
        r.x = dv * sx; r.y = dv * sy; r.z = dv * sz; r.w = dv * sw;
    }
    out4[(size_t)n * 4 + q] = r;
}

// ---- pooling: 64 sorted nodes/block, segment-accumulate, ~1 atomic flush per thread ----
__global__ __launch_bounds__(256) void k_pool(const float* __restrict__ q2, const float* __restrict__ W2,
                                              const float* __restrict__ b2, const int* __restrict__ nodeS,
                                              const int* __restrict__ batch, float* __restrict__ sums) {
    __shared__ float w[16 * 128];
    __shared__ float bsh[128];
    __shared__ float rows[64][16];
    __shared__ int   gid[64];
    int t = threadIdx.x;
    {
        const float4* wv = (const float4*)W2;
        ((float4*)w)[t * 2]     = wv[t * 2];
        ((float4*)w)[t * 2 + 1] = wv[t * 2 + 1];
    }
    if (t < 128) bsh[t] = b2[t];
    int base = blockIdx.x * 64;                 // 1563 blocks
    {
        int which = t >> 2, qq = t & 3;
        int idx = base + which;
        if (idx < N_NODES) {
            int node = nodeS[idx];
            if (qq == 0) gid[which] = batch[node];
            float4 v = ((const float4*)q2)[(size_t)node * 4 + qq];
            *(float4*)&rows[which][qq * 4] = v;
        }
    }
    __syncthreads();
    int half = t >> 7, j = t & 127;
    float acc = 0.f;
    int curg = -1;
    for (int it = 0; it < 32; ++it) {
        int wh = half * 32 + it;
        int idx = base + wh;
        if (idx >= N_NODES) break;
        int g = gid[wh];
        if (g != curg) {
            if (curg >= 0) atomicAdd(&sums[curg * 128 + j], acc);
            curg = g; acc = 0.f;
        }
        float a = bsh[j];
        #pragma unroll
        for (int kk = 0; kk < 16; ++kk) a += rows[wh][kk] * w[kk * 128 + j];
        acc += fmaxf(a, 0.f);
    }
    if (curg >= 0) atomicAdd(&sums[curg * 128 + j], acc);
}

// ---- fused MLP head + log_softmax ----
__global__ __launch_bounds__(128) void k_head(const float* __restrict__ sums, const int* __restrict__ boff,
                                              const float* __restrict__ LW1, const float* __restrict__ Lb1,
                                              const float* __restrict__ LW2, const float* __restrict__ Lb2,
                                              float* __restrict__ out) {
    __shared__ float srow[128];
    __shared__ float z1s[128];
    __shared__ float zz[2];
    int g = blockIdx.x, t = threadIdx.x;
    int cnt = boff[g + 1] - boff[g];
    float rc = 1.0f / fmaxf((float)cnt, 1.0f);
    srow[t] = sums[g * 128 + t] * rc;
    __syncthreads();
    float a = Lb1[t];
    for (int k = 0; k < 128; ++k) a += srow[k] * LW1[k * 128 + t];
    z1s[t] = fmaxf(a, 0.f);
    __syncthreads();
    if (t < 2) {
        float z = Lb2[t];
        for (int jj = 0; jj < 128; ++jj) z += z1s[jj] * LW2[jj * 2 + t];
        zz[t] = z;
    }
    __syncthreads();
    if (t < 2) {
        float m = fmaxf(zz[0], zz[1]);
        float lse = m + logf(expf(zz[0] - m) + expf(zz[1] - m));
        out[g * 2 + t] = zz[t] - lse;
    }
}

extern "C" void kernel_launch(void* const* d_in, const int* in_sizes, int n_in,
                              void* d_out, int out_size, void* d_ws, size_t ws_size,
                              hipStream_t stream) {
    const float* x   = (const float*)d_in[0];
    const int* ei    = (const int*)d_in[1];
    const int* batch = (const int*)d_in[2];
    const float* W1  = (const float*)d_in[3];
    const float* b1  = (const float*)d_in[4];
    const float* W2  = (const float*)d_in[5];
    const float* b2  = (const float*)d_in[6];
    const float* LW1 = (const float*)d_in[7];
    const float* Lb1 = (const float*)d_in[8];
    const float* LW2 = (const float*)d_in[9];
    const float* Lb2 = (const float*)d_in[10];
    const int* src = ei;
    const int* dst = ei + N_EDGES;

    char* ws = (char*)d_ws;
    int*   deg     = (int*)(ws);                  // 400000 B (aliased as cur later)
    int*   bhist   = (int*)(ws + 400000);         // 512 B
    float* sums    = (float*)(ws + 400512);       // 65536 B   (memset-covered)
    int*   bsum    = (int*)(ws + 466048);         // 2048 B
    int*   bsumOff = (int*)(ws + 468096);         // 2048 B
    int*   boff    = (int*)(ws + 470144);         // 1024 B (129 ints)
    int*   bcur    = (int*)(ws + 471168);         // 512 B
    int*   row     = (int*)(ws + 471680);         // 400128 B (100001 ints)
    float* dinv    = (float*)(ws + 871808);       // 400000 B
    int*   nodeS   = (int*)(ws + 1271808);        // 400000 B
    int*   srcS    = (int*)(ws + 1671808);        // 6400000 B
    float* A       = (float*)(ws + 8071808);      // 6400000 B (t1s, then q2)  16B-aligned
    float* B       = (float*)(ws + 14471808);     // 6400000 B (h1s)           16B-aligned
    int*   cur     = deg;
    float* out     = (float*)d_out;

    // zero atomic targets: deg + bhist + sums (contiguous prefix)
    hipMemsetAsync(ws, 0, 466048, stream);

    k_hist     <<<NBE + NB1, 256, 0, stream>>>(dst, batch, deg, bhist);
    k_scan1    <<<NB1,       256, 0, stream>>>(deg, bsum);
    k_scan2    <<<1,         512, 0, stream>>>(bsum, bsumOff, row, bhist, boff, bcur);
    k_scan3    <<<NB1,       256, 0, stream>>>(deg, bsumOff, row, cur, dinv);
    k_scatter  <<<NBE + NB1, 256, 0, stream>>>(src, dst, cur, srcS, batch, bcur, nodeS);
    k_gemm1    <<<6250,      256, 0, stream>>>(x, W1, dinv, A);
    k_gather<1><<<1563,      256, 0, stream>>>(row, srcS, (const float4*)A, dinv, b1, (float4*)B);
    k_gather<2><<<1563,      256, 0, stream>>>(row, srcS, (const float4*)B, dinv, b1, (float4*)A);
    k_pool     <<<1563,      256, 0, stream>>>(A, W2, b2, nodeS, batch, sums);
    k_head     <<<128,       128, 0, stream>>>(sums, boff, LW1, Lb1, LW2, Lb2, out);
}

// Round 5
// 320.565 us; speedup vs baseline: 2.1570x; 1.6856x over previous
//
#include <hip/hip_runtime.h>

typedef unsigned int u32;

#define N_NODES  100000
#define N_EDGES  1600000
#define N_GRAPHS 128

#define NPB      200        // nodes per bucket
#define NBUK     500        // buckets (500*200 = 100000 exactly)
#define CHUNK    8192       // edges per binning chunk
#define NCHUNK   196        // ceil(1600000/8192)
#define NHIST    (NBUK*NCHUNK)   // 98000
#define NBLKA    383        // ceil(98000/256)
#define CAP      6144       // LDS edge capacity per bucket (mean 3200)

// ---- per-chunk bucket histogram + per-graph node histogram ----
__global__ __launch_bounds__(512) void k_hist1(const int* __restrict__ dst, const int* __restrict__ batch,
                                               int* __restrict__ hist, int* __restrict__ bhist) {
    int t = threadIdx.x, b = blockIdx.x;
    if (b < NCHUNK) {
        __shared__ int lh[NBUK];
        for (int i = t; i < NBUK; i += 512) lh[i] = 0;
        __syncthreads();
        int base = b * CHUNK;
        #pragma unroll
        for (int it = 0; it < CHUNK / 512; ++it) {
            int e = base + it * 512 + t;
            if (e < N_EDGES) atomicAdd(&lh[dst[e] / NPB], 1);
        }
        __syncthreads();
        for (int i = t; i < NBUK; i += 512) hist[i * NCHUNK + b] = lh[i];
    } else {
        __shared__ int bh[N_GRAPHS];
        if (t < N_GRAPHS) bh[t] = 0;
        __syncthreads();
        int n = (b - NCHUNK) * 512 + t;
        if (n < N_NODES) atomicAdd(&bh[batch[n]], 1);
        __syncthreads();
        if (t < N_GRAPHS) atomicAdd(&bhist[t], bh[t]);
    }
}

// ---- scan stage 1: block sums of hist[98000] ----
__global__ __launch_bounds__(256) void k_scanA1(const int* __restrict__ hist, int* __restrict__ asum) {
    __shared__ int sh[256];
    int t = threadIdx.x, i = blockIdx.x * 256 + t;
    sh[t] = (i < NHIST) ? hist[i] : 0;
    __syncthreads();
    for (int off = 128; off > 0; off >>= 1) {
        if (t < off) sh[t] += sh[t + off];
        __syncthreads();
    }
    if (t == 0) asum[blockIdx.x] = sh[0];
}

// ---- scan stage 2 (1 block, 512 thr): scan asum[383]; scan bhist[128] -> boff/bcur ----
__global__ __launch_bounds__(512) void k_scanA2(const int* __restrict__ asum, int* __restrict__ asumOff,
                                                const int* __restrict__ bhist, int* __restrict__ boff,
                                                int* __restrict__ bcur) {
    __shared__ int s1[512], s2[512];
    int t = threadIdx.x;
    int v = (t < NBLKA) ? asum[t] : 0;
    s1[t] = v; __syncthreads();
    int* pa = s1; int* pb = s2;
    for (int off = 1; off < 512; off <<= 1) {
        int x = pa[t];
        if (t >= off) x += pa[t - off];
        pb[t] = x; __syncthreads();
        int* tmp = pa; pa = pb; pb = tmp;
    }
    if (t < NBLKA) asumOff[t] = pa[t] - v;
    __syncthreads();
    int hv = (t < N_GRAPHS) ? bhist[t] : 0;
    pa[t] = hv; __syncthreads();
    int* qa = pa; int* qb = pb;
    for (int off = 1; off < 512; off <<= 1) {
        int x = qa[t];
        if (t >= off) x += qa[t - off];
        qb[t] = x; __syncthreads();
        int* tmp = qa; qa = qb; qb = tmp;
    }
    if (t < N_GRAPHS) { int e = qa[t] - hv; boff[t] = e; bcur[t] = e; }
    if (t == 0) boff[N_GRAPHS] = N_NODES;
}

// ---- scan stage 3: in-place exclusive scan of hist + global offsets ----
__global__ __launch_bounds__(256) void k_scanA3(int* __restrict__ hist, const int* __restrict__ asumOff) {
    __shared__ int a1[256], a2[256];
    int t = threadIdx.x, i = blockIdx.x * 256 + t;
    int v = (i < NHIST) ? hist[i] : 0;
    a1[t] = v; __syncthreads();
    int* pa = a1; int* pb = a2;
    for (int off = 1; off < 256; off <<= 1) {
        int x = pa[t];
        if (t >= off) x += pa[t - off];
        pb[t] = x; __syncthreads();
        int* tmp = pa; pa = pb; pb = tmp;
    }
    if (i < NHIST) hist[i] = pa[t] - v + asumOff[blockIdx.x];
}

// ---- bin edges into buckets (packed u32: dloc<<24 | src) + node sort-by-graph ----
__global__ __launch_bounds__(512) void k_bin(const int* __restrict__ src, const int* __restrict__ dst,
                                             const int* __restrict__ hist, u32* __restrict__ packed,
                                             const int* __restrict__ batch, int* __restrict__ bcur,
                                             int* __restrict__ nodeS) {
    int t = threadIdx.x, b = blockIdx.x;
    if (b < NCHUNK) {
        __shared__ int cur5[NBUK];
        for (int i = t; i < NBUK; i += 512) cur5[i] = hist[i * NCHUNK + b];
        __syncthreads();
        int base = b * CHUNK;
        #pragma unroll
        for (int it = 0; it < CHUNK / 512; ++it) {
            int e = base + it * 512 + t;
            if (e < N_EDGES) {
                int d = dst[e], s = src[e];
                int bk = d / NPB;
                int pos = atomicAdd(&cur5[bk], 1);
                packed[pos] = ((u32)(d - bk * NPB) << 24) | (u32)s;
            }
        }
    } else {
        int n = (b - NCHUNK) * 512 + t;
        if (n < N_NODES) {
            int pos = atomicAdd(&bcur[batch[n]], 1);
            nodeS[pos] = n;
        }
    }
}

// ---- per-bucket local CSR: count -> local scan (row, dinv) -> LDS scatter -> dense flush ----
__global__ __launch_bounds__(256) void k_locCSR(const u32* __restrict__ packed, const int* __restrict__ hist,
                                                int* __restrict__ row, float* __restrict__ dinv,
                                                int* __restrict__ srcS) {
    __shared__ u32 lp[CAP];
    __shared__ int sbuf[CAP];
    __shared__ int cnt[NPB];
    __shared__ int s1[256], s2[256];
    int b = blockIdx.x, t = threadIdx.x;
    int start = hist[b * NCHUNK];
    int end   = (b == NBUK - 1) ? N_EDGES : hist[(b + 1) * NCHUNK];
    int len = end - start;
    for (int i = t; i < NPB; i += 256) cnt[i] = 0;
    __syncthreads();
    bool cached = (len <= CAP);
    if (cached) {
        for (int i = t; i < len; i += 256) {
            u32 p = packed[start + i];
            lp[i] = p;
            atomicAdd(&cnt[p >> 24], 1);
        }
    } else {
        for (int i = t; i < len; i += 256) {
            u32 p = packed[start + i];
            atomicAdd(&cnt[p >> 24], 1);
        }
    }
    __syncthreads();
    int v = (t < NPB) ? cnt[t] : 0;
    s1[t] = v; __syncthreads();
    int* pa = s1; int* pb = s2;
    for (int off = 1; off < 256; off <<= 1) {
        int x = pa[t];
        if (t >= off) x += pa[t - off];
        pb[t] = x; __syncthreads();
        int* tmp = pa; pa = pb; pb = tmp;
    }
    int excl = pa[t] - v;
    if (t < NPB) {
        row[b * NPB + t]  = start + excl;
        dinv[b * NPB + t] = rsqrtf((float)(v + 1));
    }
    if (b == NBUK - 1 && t == 0) row[N_NODES] = N_EDGES;
    __syncthreads();
    if (t < NPB) cnt[t] = excl;   // local running cursor
    __syncthreads();
    if (cached) {
        for (int i = t; i < len; i += 256) {
            u32 p = lp[i];
            int lpos = atomicAdd(&cnt[p >> 24], 1);
            sbuf[lpos] = (int)(p & 0xFFFFFFu);
        }
        __syncthreads();
        for (int i = t; i < len; i += 256) srcS[start + i] = sbuf[i];
    } else {
        for (int i = t; i < len; i += 256) {
            u32 p = packed[start + i];
            int lpos = atomicAdd(&cnt[p >> 24], 1);
            srcS[start + lpos] = (int)(p & 0xFFFFFFu);
        }
    }
}

// ---- t1s = dinv * (x @ W1) ----
__global__ __launch_bounds__(256) void k_gemm1(const float* __restrict__ x, const float* __restrict__ W1,
                                               const float* __restrict__ dinv, float* __restrict__ t1s) {
    __shared__ float w[128 * 16];
    __shared__ float xs[16][132];
    int t = threadIdx.x;
    {
        const float4* wv = (const float4*)W1;
        ((float4*)w)[t * 2]     = wv[t * 2];
        ((float4*)w)[t * 2 + 1] = wv[t * 2 + 1];
    }
    int base = blockIdx.x * 16;
    {
        const float4* xv = (const float4*)(x + (size_t)base * 128);
        #pragma unroll
        for (int q = 0; q < 2; ++q) {
            int i4 = t * 2 + q;
            float4 v = xv[i4];
            int idx = i4 * 4;
            *((float4*)&xs[idx >> 7][idx & 127]) = v;
        }
    }
    __syncthreads();
    int nl = t >> 4, j = t & 15;
    int n = base + nl;
    const float4* xr = (const float4*)&xs[nl][0];
    float acc = 0.f;
    #pragma unroll
    for (int k4 = 0; k4 < 32; ++k4) {
        float4 v = xr[k4];
        acc += v.x * w[(k4 * 4 + 0) * 16 + j];
        acc += v.y * w[(k4 * 4 + 1) * 16 + j];
        acc += v.z * w[(k4 * 4 + 2) * 16 + j];
        acc += v.w * w[(k4 * 4 + 3) * 16 + j];
    }
    t1s[n * 16 + j] = dinv[n] * acc;
}

// ---- CSR gather, 4 lanes/node, float4/lane, 4x unrolled independent gathers ----
template <int LAYER>
__global__ __launch_bounds__(256) void k_gather(const int* __restrict__ row, const int* __restrict__ srcS,
                                                const float4* __restrict__ hs4, const float* __restrict__ dinv,
                                                const float* __restrict__ b1, float4* __restrict__ out4) {
    int t = threadIdx.x;
    int q = t & 3;
    int n = blockIdx.x * 64 + (t >> 2);     // 1563 blocks
    if (n >= N_NODES) return;
    int r0 = row[n], r1 = row[n + 1];
    float4 a0 = hs4[(size_t)n * 4 + q];     // self-loop term
    float4 a1 = {0.f, 0.f, 0.f, 0.f};
    float4 a2 = {0.f, 0.f, 0.f, 0.f};
    float4 a3 = {0.f, 0.f, 0.f, 0.f};
    int i = r0;
    for (; i + 4 <= r1; i += 4) {
        int s0 = srcS[i], s1 = srcS[i + 1], s2 = srcS[i + 2], s3 = srcS[i + 3];
        float4 v0 = hs4[(size_t)s0 * 4 + q];
        float4 v1 = hs4[(size_t)s1 * 4 + q];
        float4 v2 = hs4[(size_t)s2 * 4 + q];
        float4 v3 = hs4[(size_t)s3 * 4 + q];
        a0.x += v0.x; a0.y += v0.y; a0.z += v0.z; a0.w += v0.w;
        a1.x += v1.x; a1.y += v1.y; a1.z += v1.z; a1.w += v1.w;
        a2.x += v2.x; a2.y += v2.y; a2.z += v2.z; a2.w += v2.w;
        a3.x += v3.x; a3.y += v3.y; a3.z += v3.z; a3.w += v3.w;
    }
    for (; i < r1; ++i) {
        int s = srcS[i];
        float4 v = hs4[(size_t)s * 4 + q];
        a0.x += v.x; a0.y += v.y; a0.z += v.z; a0.w += v.w;
    }
    float sx = (a0.x + a1.x) + (a2.x + a3.x);
    float sy = (a0.y + a1.y) + (a2.y + a3.y);
    float sz = (a0.z + a1.z) + (a2.z + a3.z);
    float sw = (a0.w + a1.w) + (a2.w + a3.w);
    float dv = dinv[n];
    float4 r;
    if (LAYER == 1) {
        const float4 bb = ((const float4*)b1)[q];
        r.x = dv * fmaxf(dv * sx + bb.x, 0.f);
        r.y = dv * fmaxf(dv * sy + bb.y, 0.f);
        r.z = dv * fmaxf(dv * sz + bb.z, 0.f);
        r.w = dv * fmaxf(dv * sw + bb.w, 0.f);
    } else {
        r.x = dv * sx; r.y = dv * sy; r.z = dv * sz; r.w = dv * sw;
    }
    out4[(size_t)n * 4 + q] = r;
}

// ---- pooling: 64 sorted nodes/block, segment-accumulate, ~1 atomic flush per thread ----
__global__ __launch_bounds__(256) void k_pool(const float* __restrict__ q2, const float* __restrict__ W2,
                                              const float* __restrict__ b2, const int* __restrict__ nodeS,
                                              const int* __restrict__ batch, float* __restrict__ sums) {
    __shared__ float w[16 * 128];
    __shared__ float bsh[128];
    __shared__ float rows[64][16];
    __shared__ int   gid[64];
    int t = threadIdx.x;
    {
        const float4* wv = (const float4*)W2;
        ((float4*)w)[t * 2]     = wv[t * 2];
        ((float4*)w)[t * 2 + 1] = wv[t * 2 + 1];
    }
    if (t < 128) bsh[t] = b2[t];
    int base = blockIdx.x * 64;                 // 1563 blocks
    {
        int which = t >> 2, qq = t & 3;
        int idx = base + which;
        if (idx < N_NODES) {
            int node = nodeS[idx];
            if (qq == 0) gid[which] = batch[node];
            float4 v = ((const float4*)q2)[(size_t)node * 4 + qq];
            *(float4*)&rows[which][qq * 4] = v;
        }
    }
    __syncthreads();
    int half = t >> 7, j = t & 127;
    float acc = 0.f;
    int curg = -1;
    for (int it = 0; it < 32; ++it) {
        int wh = half * 32 + it;
        int idx = base + wh;
        if (idx >= N_NODES) break;
        int g = gid[wh];
        if (g != curg) {
            if (curg >= 0) atomicAdd(&sums[curg * 128 + j], acc);
            curg = g; acc = 0.f;
        }
        float a = bsh[j];
        #pragma unroll
        for (int kk = 0; kk < 16; ++kk) a += rows[wh][kk] * w[kk * 128 + j];
        acc += fmaxf(a, 0.f);
    }
    if (curg >= 0) atomicAdd(&sums[curg * 128 + j], acc);
}

// ---- fused MLP head + log_softmax ----
__global__ __launch_bounds__(128) void k_head(const float* __restrict__ sums, const int* __restrict__ boff,
                                              const float* __restrict__ LW1, const float* __restrict__ Lb1,
                                              const float* __restrict__ LW2, const float* __restrict__ Lb2,
                                              float* __restrict__ out) {
    __shared__ float srow[128];
    __shared__ float z1s[128];
    __shared__ float zz[2];
    int g = blockIdx.x, t = threadIdx.x;
    int cnt = boff[g + 1] - boff[g];
    float rc = 1.0f / fmaxf((float)cnt, 1.0f);
    srow[t] = sums[g * 128 + t] * rc;
    __syncthreads();
    float a = Lb1[t];
    for (int k = 0; k < 128; ++k) a += srow[k] * LW1[k * 128 + t];
    z1s[t] = fmaxf(a, 0.f);
    __syncthreads();
    if (t < 2) {
        float z = Lb2[t];
        for (int jj = 0; jj < 128; ++jj) z += z1s[jj] * LW2[jj * 2 + t];
        zz[t] = z;
    }
    __syncthreads();
    if (t < 2) {
        float m = fmaxf(zz[0], zz[1]);
        float lse = m + logf(expf(zz[0] - m) + expf(zz[1] - m));
        out[g * 2 + t] = zz[t] - lse;
    }
}

extern "C" void kernel_launch(void* const* d_in, const int* in_sizes, int n_in,
                              void* d_out, int out_size, void* d_ws, size_t ws_size,
                              hipStream_t stream) {
    const float* x   = (const float*)d_in[0];
    const int* ei    = (const int*)d_in[1];
    const int* batch = (const int*)d_in[2];
    const float* W1  = (const float*)d_in[3];
    const float* b1  = (const float*)d_in[4];
    const float* W2  = (const float*)d_in[5];
    const float* b2  = (const float*)d_in[6];
    const float* LW1 = (const float*)d_in[7];
    const float* Lb1 = (const float*)d_in[8];
    const float* LW2 = (const float*)d_in[9];
    const float* Lb2 = (const float*)d_in[10];
    const int* src = ei;
    const int* dst = ei + N_EDGES;

    char* ws = (char*)d_ws;
    int*   bhist   = (int*)(ws);                  // 512 B
    float* sums    = (float*)(ws + 512);          // 65536 B    (memset covers [0,66048))
    int*   bcur    = (int*)(ws + 66048);          // 512 B
    int*   boff    = (int*)(ws + 66560);          // 1024 B (129 ints)
    int*   asum    = (int*)(ws + 67584);          // 1536 B (383 ints)
    int*   asumOff = (int*)(ws + 69120);          // 1536 B
    int*   hist    = (int*)(ws + 70656);          // 392000 B (98000 ints, scanned in-place)
    int*   row     = (int*)(ws + 462656);         // 400128 B (100001 ints)
    float* dinv    = (float*)(ws + 862784);       // 400000 B
    int*   nodeS   = (int*)(ws + 1262784);        // 400000 B
    int*   srcS    = (int*)(ws + 1662784);        // 6400000 B
    u32*   packed  = (u32*)(ws + 8062784);        // 6400000 B (dead after locCSR)
    float* A       = (float*)(ws + 8062784);      // overlays packed (t1s, then q2)
    float* B       = (float*)(ws + 14462784);     // 6400000 B (h1s)
    float* out     = (float*)d_out;

    // zero atomic targets: bhist + sums
    hipMemsetAsync(ws, 0, 66048, stream);

    k_hist1    <<<NCHUNK + 196, 512, 0, stream>>>(dst, batch, hist, bhist);
    k_scanA1   <<<NBLKA,        256, 0, stream>>>(hist, asum);
    k_scanA2   <<<1,            512, 0, stream>>>(asum, asumOff, bhist, boff, bcur);
    k_scanA3   <<<NBLKA,        256, 0, stream>>>(hist, asumOff);
    k_bin      <<<NCHUNK + 196, 512, 0, stream>>>(src, dst, hist, packed, batch, bcur, nodeS);
    k_locCSR   <<<NBUK,         256, 0, stream>>>(packed, hist, row, dinv, srcS);
    k_gemm1    <<<6250,         256, 0, stream>>>(x, W1, dinv, A);
    k_gather<1><<<1563,         256, 0, stream>>>(row, srcS, (const float4*)A, dinv, b1, (float4*)B);
    k_gather<2><<<1563,         256, 0, stream>>>(row, srcS, (const float4*)B, dinv, b1, (float4*)A);
    k_pool     <<<1563,         256, 0, stream>>>(A, W2, b2, nodeS, batch, sums);
    k_head     <<<128,          128, 0, stream>>>(sums, boff, LW1, Lb1, LW2, Lb2, out);
}

// Round 6
// 319.816 us; speedup vs baseline: 2.1621x; 1.0023x over previous
//
#include <hip/hip_runtime.h>

typedef unsigned int u32;

#define N_NODES  100000
#define N_EDGES  1600000
#define N_GRAPHS 128

#define NPB      200        // nodes per bucket
#define NBUK     500        // buckets (500*200 = 100000 exactly)
#define CHUNK    2048       // edges per binning chunk (small => high occupancy)
#define NCHUNK   782        // ceil(1600000/2048)
#define NHIST    (NBUK*NCHUNK)   // 391000
#define NBLKA    382        // ceil(391000/1024) scan blocks (1024 elems each)
#define NBN      196        // ceil(100000/512) node blocks
#define CAP      6144       // LDS edge capacity per bucket (mean 3200)

// ---- per-chunk bucket histogram + per-graph node histogram ----
__global__ __launch_bounds__(512) void k_hist1(const int* __restrict__ dst, const int* __restrict__ batch,
                                               int* __restrict__ hist, int* __restrict__ bhist) {
    int t = threadIdx.x, b = blockIdx.x;
    if (b < NCHUNK) {
        __shared__ int lh[NBUK];
        for (int i = t; i < NBUK; i += 512) lh[i] = 0;
        __syncthreads();
        int base = b * CHUNK;
        #pragma unroll
        for (int it = 0; it < CHUNK / 512; ++it) {
            int e = base + it * 512 + t;
            if (e < N_EDGES) atomicAdd(&lh[dst[e] / NPB], 1);
        }
        __syncthreads();
        for (int i = t; i < NBUK; i += 512) hist[i * NCHUNK + b] = lh[i];
    } else {
        __shared__ int bh[N_GRAPHS];
        if (t < N_GRAPHS) bh[t] = 0;
        __syncthreads();
        int n = (b - NCHUNK) * 512 + t;
        if (n < N_NODES) atomicAdd(&bh[batch[n]], 1);
        __syncthreads();
        if (t < N_GRAPHS) atomicAdd(&bhist[t], bh[t]);
    }
}

// ---- scan stage 1: 1024-element tile sums of hist ----
__global__ __launch_bounds__(256) void k_scanA1(const int* __restrict__ hist, int* __restrict__ asum) {
    __shared__ int sh[256];
    int t = threadIdx.x;
    int base = blockIdx.x * 1024 + t * 4;
    int s = 0;
    #pragma unroll
    for (int q = 0; q < 4; ++q) { int i = base + q; if (i < NHIST) s += hist[i]; }
    sh[t] = s; __syncthreads();
    for (int off = 128; off > 0; off >>= 1) {
        if (t < off) sh[t] += sh[t + off];
        __syncthreads();
    }
    if (t == 0) asum[blockIdx.x] = sh[0];
}

// ---- scan stage 2 (1 block, 512 thr): scan asum[382]; scan bhist[128] -> boff/bcur ----
__global__ __launch_bounds__(512) void k_scanA2(const int* __restrict__ asum, int* __restrict__ asumOff,
                                                const int* __restrict__ bhist, int* __restrict__ boff,
                                                int* __restrict__ bcur) {
    __shared__ int s1[512], s2[512];
    int t = threadIdx.x;
    int v = (t < NBLKA) ? asum[t] : 0;
    s1[t] = v; __syncthreads();
    int* pa = s1; int* pb = s2;
    for (int off = 1; off < 512; off <<= 1) {
        int x = pa[t];
        if (t >= off) x += pa[t - off];
        pb[t] = x; __syncthreads();
        int* tmp = pa; pa = pb; pb = tmp;
    }
    if (t < NBLKA) asumOff[t] = pa[t] - v;
    __syncthreads();
    int hv = (t < N_GRAPHS) ? bhist[t] : 0;
    pa[t] = hv; __syncthreads();
    int* qa = pa; int* qb = pb;
    for (int off = 1; off < 512; off <<= 1) {
        int x = qa[t];
        if (t >= off) x += qa[t - off];
        qb[t] = x; __syncthreads();
        int* tmp = qa; qa = qb; qb = tmp;
    }
    if (t < N_GRAPHS) { int e = qa[t] - hv; boff[t] = e; bcur[t] = e; }
    if (t == 0) boff[N_GRAPHS] = N_NODES;
}

// ---- scan stage 3: in-place exclusive scan of hist (4 consecutive/thread) + global offsets ----
__global__ __launch_bounds__(256) void k_scanA3(int* __restrict__ hist, const int* __restrict__ asumOff) {
    __shared__ int s1[256], s2[256];
    int t = threadIdx.x;
    int base = blockIdx.x * 1024 + t * 4;
    int v0 = 0, v1 = 0, v2 = 0, v3 = 0;
    if (base     < NHIST) v0 = hist[base];
    if (base + 1 < NHIST) v1 = hist[base + 1];
    if (base + 2 < NHIST) v2 = hist[base + 2];
    if (base + 3 < NHIST) v3 = hist[base + 3];
    int s = v0 + v1 + v2 + v3;
    s1[t] = s; __syncthreads();
    int* pa = s1; int* pb = s2;
    for (int off = 1; off < 256; off <<= 1) {
        int x = pa[t];
        if (t >= off) x += pa[t - off];
        pb[t] = x; __syncthreads();
        int* tmp = pa; pa = pb; pb = tmp;
    }
    int excl = pa[t] - s + asumOff[blockIdx.x];
    if (base     < NHIST) hist[base]     = excl;
    if (base + 1 < NHIST) hist[base + 1] = excl + v0;
    if (base + 2 < NHIST) hist[base + 2] = excl + v0 + v1;
    if (base + 3 < NHIST) hist[base + 3] = excl + v0 + v1 + v2;
}

// ---- bin edges into buckets (packed u32: dloc<<24 | src) + node sort-by-graph ----
__global__ __launch_bounds__(512) void k_bin(const int* __restrict__ src, const int* __restrict__ dst,
                                             const int* __restrict__ hist, u32* __restrict__ packed,
                                             const int* __restrict__ batch, int* __restrict__ bcur,
                                             int* __restrict__ nodeS) {
    int t = threadIdx.x, b = blockIdx.x;
    if (b < NCHUNK) {
        __shared__ int cur5[NBUK];
        for (int i = t; i < NBUK; i += 512) cur5[i] = hist[i * NCHUNK + b];
        __syncthreads();
        int base = b * CHUNK;
        #pragma unroll
        for (int it = 0; it < CHUNK / 512; ++it) {
            int e = base + it * 512 + t;
            if (e < N_EDGES) {
                int d = dst[e], s = src[e];
                int bk = d / NPB;
                int pos = atomicAdd(&cur5[bk], 1);
                packed[pos] = ((u32)(d - bk * NPB) << 24) | (u32)s;
            }
        }
    } else {
        int n = (b - NCHUNK) * 512 + t;
        if (n < N_NODES) {
            int pos = atomicAdd(&bcur[batch[n]], 1);
            nodeS[pos] = n;
        }
    }
}

// ---- per-bucket local CSR: count -> local scan (row, dinv) -> LDS scatter -> dense flush ----
__global__ __launch_bounds__(256) void k_locCSR(const u32* __restrict__ packed, const int* __restrict__ hist,
                                                int* __restrict__ row, float* __restrict__ dinv,
                                                int* __restrict__ srcS) {
    __shared__ u32 lp[CAP];
    __shared__ int sbuf[CAP];
    __shared__ int cnt[NPB];
    __shared__ int s1[256], s2[256];
    int b = blockIdx.x, t = threadIdx.x;
    int start = hist[b * NCHUNK];
    int end   = (b == NBUK - 1) ? N_EDGES : hist[(b + 1) * NCHUNK];
    int len = end - start;
    for (int i = t; i < NPB; i += 256) cnt[i] = 0;
    __syncthreads();
    bool cached = (len <= CAP);
    if (cached) {
        for (int i = t; i < len; i += 256) {
            u32 p = packed[start + i];
            lp[i] = p;
            atomicAdd(&cnt[p >> 24], 1);
        }
    } else {
        for (int i = t; i < len; i += 256) {
            u32 p = packed[start + i];
            atomicAdd(&cnt[p >> 24], 1);
        }
    }
    __syncthreads();
    int v = (t < NPB) ? cnt[t] : 0;
    s1[t] = v; __syncthreads();
    int* pa = s1; int* pb = s2;
    for (int off = 1; off < 256; off <<= 1) {
        int x = pa[t];
        if (t >= off) x += pa[t - off];
        pb[t] = x; __syncthreads();
        int* tmp = pa; pa = pb; pb = tmp;
    }
    int excl = pa[t] - v;
    if (t < NPB) {
        row[b * NPB + t]  = start + excl;
        dinv[b * NPB + t] = rsqrtf((float)(v + 1));
    }
    if (b == NBUK - 1 && t == 0) row[N_NODES] = N_EDGES;
    __syncthreads();
    if (t < NPB) cnt[t] = excl;   // local running cursor
    __syncthreads();
    if (cached) {
        for (int i = t; i < len; i += 256) {
            u32 p = lp[i];
            int lpos = atomicAdd(&cnt[p >> 24], 1);
            sbuf[lpos] = (int)(p & 0xFFFFFFu);
        }
        __syncthreads();
        for (int i = t; i < len; i += 256) srcS[start + i] = sbuf[i];
    } else {
        for (int i = t; i < len; i += 256) {
            u32 p = packed[start + i];
            int lpos = atomicAdd(&cnt[p >> 24], 1);
            srcS[start + lpos] = (int)(p & 0xFFFFFFu);
        }
    }
}

// ---- t1s = dinv * (x @ W1) ----
__global__ __launch_bounds__(256) void k_gemm1(const float* __restrict__ x, const float* __restrict__ W1,
                                               const float* __restrict__ dinv, float* __restrict__ t1s) {
    __shared__ float w[128 * 16];
    __shared__ float xs[16][132];
    int t = threadIdx.x;
    {
        const float4* wv = (const float4*)W1;
        ((float4*)w)[t * 2]     = wv[t * 2];
        ((float4*)w)[t * 2 + 1] = wv[t * 2 + 1];
    }
    int base = blockIdx.x * 16;
    {
        const float4* xv = (const float4*)(x + (size_t)base * 128);
        #pragma unroll
        for (int q = 0; q < 2; ++q) {
            int i4 = t * 2 + q;
            float4 v = xv[i4];
            int idx = i4 * 4;
            *((float4*)&xs[idx >> 7][idx & 127]) = v;
        }
    }
    __syncthreads();
    int nl = t >> 4, j = t & 15;
    int n = base + nl;
    const float4* xr = (const float4*)&xs[nl][0];
    float acc = 0.f;
    #pragma unroll
    for (int k4 = 0; k4 < 32; ++k4) {
        float4 v = xr[k4];
        acc += v.x * w[(k4 * 4 + 0) * 16 + j];
        acc += v.y * w[(k4 * 4 + 1) * 16 + j];
        acc += v.z * w[(k4 * 4 + 2) * 16 + j];
        acc += v.w * w[(k4 * 4 + 3) * 16 + j];
    }
    t1s[n * 16 + j] = dinv[n] * acc;
}

// ---- CSR gather, 4 lanes/node, float4/lane, 4x unrolled independent gathers ----
template <int LAYER>
__global__ __launch_bounds__(256) void k_gather(const int* __restrict__ row, const int* __restrict__ srcS,
                                                const float4* __restrict__ hs4, const float* __restrict__ dinv,
                                                const float* __restrict__ b1, float4* __restrict__ out4) {
    int t = threadIdx.x;
    int q = t & 3;
    int n = blockIdx.x * 64 + (t >> 2);     // 1563 blocks
    if (n >= N_NODES) return;
    int r0 = row[n], r1 = row[n + 1];
    float4 a0 = hs4[(size_t)n * 4 + q];     // self-loop term
    float4 a1 = {0.f, 0.f, 0.f, 0.f};
    float4 a2 = {0.f, 0.f, 0.f, 0.f};
    float4 a3 = {0.f, 0.f, 0.f, 0.f};
    int i = r0;
    for (; i + 4 <= r1; i += 4) {
        int s0 = srcS[i], s1 = srcS[i + 1], s2 = srcS[i + 2], s3 = srcS[i + 3];
        float4 v0 = hs4[(size_t)s0 * 4 + q];
        float4 v1 = hs4[(size_t)s1 * 4 + q];
        float4 v2 = hs4[(size_t)s2 * 4 + q];
        float4 v3 = hs4[(size_t)s3 * 4 + q];
        a0.x += v0.x; a0.y += v0.y; a0.z += v0.z; a0.w += v0.w;
        a1.x += v1.x; a1.y += v1.y; a1.z += v1.z; a1.w += v1.w;
        a2.x += v2.x; a2.y += v2.y; a2.z += v2.z; a2.w += v2.w;
        a3.x += v3.x; a3.y += v3.y; a3.z += v3.z; a3.w += v3.w;
    }
    for (; i < r1; ++i) {
        int s = srcS[i];
        float4 v = hs4[(size_t)s * 4 + q];
        a0.x += v.x; a0.y += v.y; a0.z += v.z; a0.w += v.w;
    }
    float sx = (a0.x + a1.x) + (a2.x + a3.x);
    float sy = (a0.y + a1.y) + (a2.y + a3.y);
    float sz = (a0.z + a1.z) + (a2.z + a3.z);
    float sw = (a0.w + a1.w) + (a2.w + a3.w);
    float dv = dinv[n];
    float4 r;
    if (LAYER == 1) {
        const float4 bb = ((const float4*)b1)[q];
        r.x = dv * fmaxf(dv * sx + bb.x, 0.f);
        r.y = dv * fmaxf(dv * sy + bb.y, 0.f);
        r.z = dv * fmaxf(dv * sz + bb.z, 0.f);
        r.w = dv * fmaxf(dv * sw + bb.w, 0.f);
    } else {
        r.x = dv * sx; r.y = dv * sy; r.z = dv * sz; r.w = dv * sw;
    }
    out4[(size_t)n * 4 + q] = r;
}

// ---- pooling: 64 sorted nodes/block, segment-accumulate, ~1 atomic flush per thread ----
__global__ __launch_bounds__(256) void k_pool(const float* __restrict__ q2, const float* __restrict__ W2,
                                              const float* __restrict__ b2, const int* __restrict__ nodeS,
                                              const int* __restrict__ batch, float* __restrict__ sums) {
    __shared__ float w[16 * 128];
    __shared__ float bsh[128];
    __shared__ float rows[64][16];
    __shared__ int   gid[64];
    int t = threadIdx.x;
    {
        const float4* wv = (const float4*)W2;
        ((float4*)w)[t * 2]     = wv[t * 2];
        ((float4*)w)[t * 2 + 1] = wv[t * 2 + 1];
    }
    if (t < 128) bsh[t] = b2[t];
    int base = blockIdx.x * 64;                 // 1563 blocks
    {
        int which = t >> 2, qq = t & 3;
        int idx = base + which;
        if (idx < N_NODES) {
            int node = nodeS[idx];
            if (qq == 0) gid[which] = batch[node];
            float4 v = ((const float4*)q2)[(size_t)node * 4 + qq];
            *(float4*)&rows[which][qq * 4] = v;
        }
    }
    __syncthreads();
    int half = t >> 7, j = t & 127;
    float acc = 0.f;
    int curg = -1;
    for (int it = 0; it < 32; ++it) {
        int wh = half * 32 + it;
        int idx = base + wh;
        if (idx >= N_NODES) break;
        int g = gid[wh];
        if (g != curg) {
            if (curg >= 0) atomicAdd(&sums[curg * 128 + j], acc);
            curg = g; acc = 0.f;
        }
        float a = bsh[j];
        #pragma unroll
        for (int kk = 0; kk < 16; ++kk) a += rows[wh][kk] * w[kk * 128 + j];
        acc += fmaxf(a, 0.f);
    }
    if (curg >= 0) atomicAdd(&sums[curg * 128 + j], acc);
}

// ---- fused MLP head + log_softmax ----
__global__ __launch_bounds__(128) void k_head(const float* __restrict__ sums, const int* __restrict__ boff,
                                              const float* __restrict__ LW1, const float* __restrict__ Lb1,
                                              const float* __restrict__ LW2, const float* __restrict__ Lb2,
                                              float* __restrict__ out) {
    __shared__ float srow[128];
    __shared__ float z1s[128];
    __shared__ float zz[2];
    int g = blockIdx.x, t = threadIdx.x;
    int cnt = boff[g + 1] - boff[g];
    float rc = 1.0f / fmaxf((float)cnt, 1.0f);
    srow[t] = sums[g * 128 + t] * rc;
    __syncthreads();
    float a = Lb1[t];
    for (int k = 0; k < 128; ++k) a += srow[k] * LW1[k * 128 + t];
    z1s[t] = fmaxf(a, 0.f);
    __syncthreads();
    if (t < 2) {
        float z = Lb2[t];
        for (int jj = 0; jj < 128; ++jj) z += z1s[jj] * LW2[jj * 2 + t];
        zz[t] = z;
    }
    __syncthreads();
    if (t < 2) {
        float m = fmaxf(zz[0], zz[1]);
        float lse = m + logf(expf(zz[0] - m) + expf(zz[1] - m));
        out[g * 2 + t] = zz[t] - lse;
    }
}

extern "C" void kernel_launch(void* const* d_in, const int* in_sizes, int n_in,
                              void* d_out, int out_size, void* d_ws, size_t ws_size,
                              hipStream_t stream) {
    const float* x   = (const float*)d_in[0];
    const int* ei    = (const int*)d_in[1];
    const int* batch = (const int*)d_in[2];
    const float* W1  = (const float*)d_in[3];
    const float* b1  = (const float*)d_in[4];
    const float* W2  = (const float*)d_in[5];
    const float* b2  = (const float*)d_in[6];
    const float* LW1 = (const float*)d_in[7];
    const float* Lb1 = (const float*)d_in[8];
    const float* LW2 = (const float*)d_in[9];
    const float* Lb2 = (const float*)d_in[10];
    const int* src = ei;
    const int* dst = ei + N_EDGES;

    char* ws = (char*)d_ws;
    int*   bhist   = (int*)(ws);                  // 512 B
    float* sums    = (float*)(ws + 512);          // 65536 B    (memset covers [0,66048))
    int*   bcur    = (int*)(ws + 66048);          // 512 B
    int*   boff    = (int*)(ws + 66560);          // 1024 B (129 ints)
    int*   asum    = (int*)(ws + 67584);          // 1536 B (382 ints)
    int*   asumOff = (int*)(ws + 69120);          // 1536 B
    int*   row     = (int*)(ws + 70656);          // 400128 B (100001 ints)
    float* dinv    = (float*)(ws + 470784);       // 400000 B
    int*   nodeS   = (int*)(ws + 870784);         // 400000 B
    int*   srcS    = (int*)(ws + 1270784);        // 6400000 B
    u32*   packed  = (u32*)(ws + 7670784);        // 6400000 B (dead after locCSR)
    float* A       = (float*)(ws + 7670784);      // overlays packed (t1s, then q2) 16B-aligned
    float* B       = (float*)(ws + 14070784);     // 6400000 B (h1s) 16B-aligned
    int*   hist    = (int*)(ws + 14070784);       // 1564000 B, overlays B (dead before B written)
    float* out     = (float*)d_out;

    // zero atomic targets: bhist + sums
    hipMemsetAsync(ws, 0, 66048, stream);

    k_hist1    <<<NCHUNK + NBN, 512, 0, stream>>>(dst, batch, hist, bhist);
    k_scanA1   <<<NBLKA,        256, 0, stream>>>(hist, asum);
    k_scanA2   <<<1,            512, 0, stream>>>(asum, asumOff, bhist, boff, bcur);
    k_scanA3   <<<NBLKA,        256, 0, stream>>>(hist, asumOff);
    k_bin      <<<NCHUNK + NBN, 512, 0, stream>>>(src, dst, hist, packed, batch, bcur, nodeS);
    k_locCSR   <<<NBUK,         256, 0, stream>>>(packed, hist, row, dinv, srcS);
    k_gemm1    <<<6250,         256, 0, stream>>>(x, W1, dinv, A);
    k_gather<1><<<1563,         256, 0, stream>>>(row, srcS, (const float4*)A, dinv, b1, (float4*)B);
    k_gather<2><<<1563,         256, 0, stream>>>(row, srcS, (const float4*)B, dinv, b1, (float4*)A);
    k_pool     <<<1563,         256, 0, stream>>>(A, W2, b2, nodeS, batch, sums);
    k_head     <<<128,          128, 0, stream>>>(sums, boff, LW1, Lb1, LW2, Lb2, out);
}